// Round 2
// baseline (2661.844 us; speedup 1.0000x reference)
//
#include <hip/hip_runtime.h>
#include <hip/hip_bf16.h>
#include <math.h>

#define NTOK 16384
#define DDIM 1024
#define HDIM 4096
#define NEXP 8

typedef __bf16 bf16_t;
typedef __bf16 bf16x8 __attribute__((ext_vector_type(8)));
typedef float f32x4 __attribute__((ext_vector_type(4)));

__device__ __forceinline__ void gld16(const bf16_t* g, bf16_t* l) {
    __builtin_amdgcn_global_load_lds(
        (const __attribute__((address_space(1))) void*)g,
        (__attribute__((address_space(3))) void*)l, 16, 0, 0);
}

// ---------------- small utility kernels ----------------

__global__ void init_counts(int* counts) {
    if (threadIdx.x < NEXP) counts[threadIdx.x] = 0;
}

__global__ void zero_out_kernel(float4* p) {
    p[(size_t)blockIdx.x * 256 + threadIdx.x] = make_float4(0.f, 0.f, 0.f, 0.f);
}

// ---------------- router: fp32 exact ----------------
// one wave per token; lanes split D; 8 accumulators; butterfly reduce.
__global__ void router_kernel(const float* __restrict__ x, const float* __restrict__ grad,
                              const float* __restrict__ rW, const float* __restrict__ rb,
                              float* __restrict__ probs, int* __restrict__ t2i,
                              float* __restrict__ t2g, int* __restrict__ counts) {
    const int lane = threadIdx.x & 63;
    const int n = blockIdx.x * 4 + (threadIdx.x >> 6);
    float acc[NEXP];
#pragma unroll
    for (int e = 0; e < NEXP; ++e) acc[e] = 0.f;
    const float* xr = x + (size_t)n * DDIM;
    for (int d = lane; d < DDIM; d += 64) {
        float xv = xr[d];
        const float* rr = rW + (size_t)d * NEXP;
#pragma unroll
        for (int e = 0; e < NEXP; ++e) acc[e] = fmaf(xv, rr[e], acc[e]);
    }
#pragma unroll
    for (int e = 0; e < NEXP; ++e) {
#pragma unroll
        for (int off = 32; off > 0; off >>= 1)
            acc[e] += __shfl_xor(acc[e], off, 64);
    }
    if (lane == 0) {
        float gv = grad[n];
        float p[NEXP];
        float mx = -1e30f;
#pragma unroll
        for (int e = 0; e < NEXP; ++e) {
            p[e] = acc[e] + gv * rW[(size_t)DDIM * NEXP + e] + rb[e];
            mx = fmaxf(mx, p[e]);
        }
        float s = 0.f;
#pragma unroll
        for (int e = 0; e < NEXP; ++e) { p[e] = expf(p[e] - mx); s += p[e]; }
        float inv = 1.f / s;
        int i1 = 0; float v1 = -1.f;
#pragma unroll
        for (int e = 0; e < NEXP; ++e) {
            p[e] *= inv;
            probs[(size_t)n * NEXP + e] = p[e];
            if (p[e] > v1) { v1 = p[e]; i1 = e; }   // strict > : lowest index wins ties (top_k semantics)
        }
        int i2 = 0; float v2 = -2.f;
#pragma unroll
        for (int e = 0; e < NEXP; ++e) {
            if (e != i1 && p[e] > v2) { v2 = p[e]; i2 = e; }
        }
        t2i[n * 2] = i1; t2i[n * 2 + 1] = i2;
        t2g[n * 2] = v1; t2g[n * 2 + 1] = v2;
        atomicAdd(&counts[i1], 1);
        atomicAdd(&counts[i2], 1);
    }
}

// offsets: exact prefix (for packed Xg slots) + 128-padded prefix (for fused Hbuf regions)
__global__ void offsets_kernel(const int* __restrict__ counts, int* __restrict__ offsets,
                               int* __restrict__ cursor, int* __restrict__ hoff) {
    if (threadIdx.x == 0) {
        int s = 0, hs = 0;
        for (int e = 0; e < NEXP; ++e) {
            offsets[e] = s; cursor[e] = s; hoff[e] = hs;
            s += counts[e];
            hs += (counts[e] + 127) & ~127;   // 128-row padded region per expert
        }
    }
}

__global__ void build_lists(const int* __restrict__ t2i, const float* __restrict__ t2g,
                            int* __restrict__ cursor, int* __restrict__ tok,
                            float* __restrict__ gate) {
    int n = blockIdx.x * 256 + threadIdx.x;
#pragma unroll
    for (int k = 0; k < 2; ++k) {
        int e = t2i[n * 2 + k];
        int slot = atomicAdd(&cursor[e], 1);
        tok[slot] = n;
        gate[slot] = t2g[n * 2 + k];
    }
}

// gather x rows (fp32) -> Xg (bf16), one block per gathered row
__global__ void gather_kernel(const float* __restrict__ x, const int* __restrict__ tok,
                              bf16_t* __restrict__ Xg) {
    const int r = blockIdx.x;
    const int t = threadIdx.x;
    const int token = tok[r];
    float4 v = ((const float4*)(x + (size_t)token * DDIM))[t];
    bf16_t o[4] = { (bf16_t)v.x, (bf16_t)v.y, (bf16_t)v.z, (bf16_t)v.w };
    *(uint2*)(Xg + (size_t)r * DDIM + t * 4) = *(const uint2*)o;
}

// transpose + cast: in [R][C] fp32 -> out [C][R] bf16, per expert (blockIdx.z)
__global__ void transpose_cast(const float* __restrict__ in, bf16_t* __restrict__ out,
                               int R, int C) {
    __shared__ float tile[32][33];
    const size_t ebase = (size_t)blockIdx.z * R * C;
    const int c0 = blockIdx.x * 32, r0 = blockIdx.y * 32;
    const int tx = threadIdx.x, ty = threadIdx.y;  // (32, 8)
#pragma unroll
    for (int j = 0; j < 32; j += 8)
        tile[ty + j][tx] = in[ebase + (size_t)(r0 + ty + j) * C + c0 + tx];
    __syncthreads();
#pragma unroll
    for (int j = 0; j < 32; j += 8)
        out[ebase + (size_t)(c0 + ty + j) * R + r0 + tx] = (bf16_t)tile[tx][ty + j];
}

// ---------------- MFMA GEMM (m97 structure) ----------------
// C[M,N] = A[M,K] @ B^T[N,K], bf16 in / fp32 acc. 128x128 tile, BK=64.
// EPI=0: GEMM1 -> h = gelu(C + b1) stored bf16.  EPI=1: GEMM2 -> out[tok] += gate*(C + b2).
template <int K, int EPI>
__global__ __launch_bounds__(256)
void moe_gemm(const bf16_t* __restrict__ A, const bf16_t* __restrict__ B,
              const float* __restrict__ bias, bf16_t* __restrict__ Hout,
              float* __restrict__ Out, const int* __restrict__ counts,
              const int* __restrict__ offsets, const int* __restrict__ hoff,
              const int* __restrict__ tok, const float* __restrict__ gate,
              int e_fixed, int hglobal) {
    const int e = (gridDim.z > 1) ? blockIdx.z : e_fixed;
    const int count = counts[e];
    const int m0 = blockIdx.y * 128;
    if (m0 >= count) return;
    const int off = offsets[e];
    const int n0 = blockIdx.x * 128;
    const int hbase = hglobal ? hoff[e] : 0;   // 128-padded private region per expert

    const bf16_t* Ap = (EPI == 0) ? A + ((size_t)off + m0) * K
                                  : A + ((size_t)hbase + m0) * K;
    const bf16_t* Bp = B + (size_t)e * HDIM * DDIM + (size_t)n0 * K;
    const float* bp = bias + (size_t)e * (EPI == 0 ? HDIM : DDIM) + n0;

    __shared__ __align__(16) bf16_t ldsA[128 * 64];
    __shared__ __align__(16) bf16_t ldsB[128 * 64];

    const int tid = threadIdx.x;
    const int lane = tid & 63;
    const int wv = tid >> 6;
    const int wm = (wv & 1) << 6;
    const int wn = (wv >> 1) << 6;

    f32x4 acc[4][4];
    const f32x4 zf = {0.f, 0.f, 0.f, 0.f};
#pragma unroll
    for (int i = 0; i < 4; ++i)
#pragma unroll
        for (int j = 0; j < 4; ++j) acc[i][j] = zf;

    // segment-major LDS layout: seg s = ks*128 + row; LDS bytes = s*16
    int sr[4], sk[4];
#pragma unroll
    for (int i = 0; i < 4; ++i) { int s = i * 256 + tid; sk[i] = s >> 7; sr[i] = s & 127; }

    for (int k0 = 0; k0 < K; k0 += 64) {
#pragma unroll
        for (int i = 0; i < 4; ++i) {
            gld16(Ap + (size_t)sr[i] * K + (k0 + sk[i] * 8), &ldsA[(size_t)(i * 256 + tid) * 8]);
            gld16(Bp + (size_t)sr[i] * K + (k0 + sk[i] * 8), &ldsB[(size_t)(i * 256 + tid) * 8]);
        }
        __syncthreads();
#pragma unroll
        for (int ki = 0; ki < 2; ++ki) {
            const int ks = ki * 4 + (lane >> 4);
            const int lm = lane & 15;
            bf16x8 af[4], bfr[4];
#pragma unroll
            for (int mt = 0; mt < 4; ++mt)
                af[mt] = *(const bf16x8*)&ldsA[(size_t)((ks * 128) + wm + mt * 16 + lm) * 8];
#pragma unroll
            for (int nt = 0; nt < 4; ++nt)
                bfr[nt] = *(const bf16x8*)&ldsB[(size_t)((ks * 128) + wn + nt * 16 + lm) * 8];
#pragma unroll
            for (int mt = 0; mt < 4; ++mt)
#pragma unroll
                for (int nt = 0; nt < 4; ++nt)
                    acc[mt][nt] = __builtin_amdgcn_mfma_f32_16x16x32_bf16(
                        af[mt], bfr[nt], acc[mt][nt], 0, 0, 0);
        }
        __syncthreads();
    }

    const int lm = lane & 15;
    const int lq = lane >> 4;
    if (EPI == 0) {
#pragma unroll
        for (int nt = 0; nt < 4; ++nt) {
            const int ncol = n0 + wn + nt * 16 + lm;
            const float bv = bp[wn + nt * 16 + lm];
#pragma unroll
            for (int mt = 0; mt < 4; ++mt) {
#pragma unroll
                for (int r = 0; r < 4; ++r) {
                    const int row = m0 + wm + mt * 16 + lq * 4 + r;
                    float v = acc[mt][nt][r] + bv;
                    float gl = 0.5f * v * (1.f + erff(v * 0.70710678118654752f));
                    Hout[((size_t)hbase + row) * HDIM + ncol] = (bf16_t)gl;
                }
            }
        }
    } else {
#pragma unroll
        for (int mt = 0; mt < 4; ++mt) {
#pragma unroll
            for (int r = 0; r < 4; ++r) {
                const int row = m0 + wm + mt * 16 + lq * 4 + r;
                if (row < count) {
                    const int slot = off + row;
                    const int token = tok[slot];
                    const float g = gate[slot];
                    float* orow = Out + (size_t)token * DDIM + n0 + wn + lm;
#pragma unroll
                    for (int nt = 0; nt < 4; ++nt) {
                        const float v = acc[mt][nt][r] + bp[wn + nt * 16 + lm];
                        atomicAdd(orow + nt * 16, g * v);
                    }
                }
            }
        }
    }
}

// ---------------- launch ----------------

extern "C" void kernel_launch(void* const* d_in, const int* in_sizes, int n_in,
                              void* d_out, int out_size, void* d_ws, size_t ws_size,
                              hipStream_t stream) {
    const float* x    = (const float*)d_in[0];
    const float* grad = (const float*)d_in[1];
    const float* rW   = (const float*)d_in[2];
    const float* rb   = (const float*)d_in[3];
    const float* W1   = (const float*)d_in[4];
    const float* b1   = (const float*)d_in[5];
    const float* W2   = (const float*)d_in[6];
    const float* b2   = (const float*)d_in[7];
    float* out   = (float*)d_out;                 // [N][D]
    float* probs = out + (size_t)NTOK * DDIM;     // [N][E]

    char* base = (char*)d_ws;
    size_t p = 0;
    auto alloc = [&](size_t bytes) -> void* {
        void* r = base + p;
        p = (p + bytes + 255) & ~(size_t)255;
        return r;
    };

    int*    counts  = (int*)alloc(4 * NEXP * sizeof(int));
    int*    offsets = counts + NEXP;
    int*    cursor  = offsets + NEXP;
    int*    hoff    = cursor + NEXP;
    int*    t2i  = (int*)alloc((size_t)NTOK * 2 * sizeof(int));
    float*  t2g  = (float*)alloc((size_t)NTOK * 2 * sizeof(float));
    int*    tok  = (int*)alloc((size_t)2 * NTOK * sizeof(int));
    float*  gate = (float*)alloc((size_t)2 * NTOK * sizeof(float));
    bf16_t* Xg   = (bf16_t*)alloc(((size_t)2 * NTOK + 128) * DDIM * sizeof(bf16_t));
    bf16_t* W1t  = (bf16_t*)alloc((size_t)NEXP * HDIM * DDIM * sizeof(bf16_t));
    bf16_t* W2t  = (bf16_t*)alloc((size_t)NEXP * HDIM * DDIM * sizeof(bf16_t));

    // fused Hbuf: every expert region padded to 128 rows -> max 2*NTOK + NEXP*128 rows
    const size_t hFused = ((size_t)2 * NTOK + NEXP * 128) * HDIM * sizeof(bf16_t);
    const size_t hSeq   = ((size_t)NTOK + 128) * HDIM * sizeof(bf16_t);
    const bool fused = (ws_size >= p + hFused);
    bf16_t* Hbuf = (bf16_t*)alloc(fused ? hFused : hSeq);

    hipLaunchKernelGGL(init_counts, dim3(1), dim3(64), 0, stream, counts);
    hipLaunchKernelGGL(zero_out_kernel, dim3((NTOK * DDIM / 4) / 256), dim3(256), 0, stream,
                       (float4*)out);
    hipLaunchKernelGGL(router_kernel, dim3(NTOK / 4), dim3(256), 0, stream,
                       x, grad, rW, rb, probs, t2i, t2g, counts);
    hipLaunchKernelGGL(offsets_kernel, dim3(1), dim3(64), 0, stream, counts, offsets, cursor, hoff);
    hipLaunchKernelGGL(build_lists, dim3(NTOK / 256), dim3(256), 0, stream,
                       t2i, t2g, cursor, tok, gate);
    hipLaunchKernelGGL(gather_kernel, dim3(2 * NTOK), dim3(256), 0, stream, x, tok, Xg);
    hipLaunchKernelGGL(transpose_cast, dim3(HDIM / 32, DDIM / 32, NEXP), dim3(32, 8), 0, stream,
                       W1, W1t, DDIM, HDIM);
    hipLaunchKernelGGL(transpose_cast, dim3(DDIM / 32, HDIM / 32, NEXP), dim3(32, 8), 0, stream,
                       W2, W2t, HDIM, DDIM);

    if (fused) {
        hipLaunchKernelGGL((moe_gemm<DDIM, 0>), dim3(HDIM / 128, NTOK / 128, NEXP), dim3(256), 0,
                           stream, Xg, W1t, b1, Hbuf, nullptr, counts, offsets, hoff, tok, gate, 0, 1);
        hipLaunchKernelGGL((moe_gemm<HDIM, 1>), dim3(DDIM / 128, NTOK / 128, NEXP), dim3(256), 0,
                           stream, Hbuf, W2t, b2, nullptr, out, counts, offsets, hoff, tok, gate, 0, 1);
    } else {
        for (int e = 0; e < NEXP; ++e) {
            hipLaunchKernelGGL((moe_gemm<DDIM, 0>), dim3(HDIM / 128, NTOK / 128, 1), dim3(256), 0,
                               stream, Xg, W1t, b1, Hbuf, nullptr, counts, offsets, hoff, tok, gate, e, 0);
            hipLaunchKernelGGL((moe_gemm<HDIM, 1>), dim3(DDIM / 128, NTOK / 128, 1), dim3(256), 0,
                               stream, Hbuf, W2t, b2, nullptr, out, counts, offsets, hoff, tok, gate, e, 0);
        }
    }
}